// Round 4
// baseline (243.734 us; speedup 1.0000x reference)
//
#include <hip/hip_runtime.h>
#include <hip/hip_bf16.h>

#define NUM_GENES 4384
#define GPAD 4608        // 18 * 256 (pad resident dim; 256 rows per block)
#define DM 128
#define ROWB 256         // bytes per bf16 row (128*2)
#define LDS_STRIDE 272   // 256 + 16B pad (b128 4-way floor)
#define NTILES 137       // 4384 / 32 (stream dim exact; pad rows never streamed)
#define RB_BLOCKS 18     // GPAD / 256
#define NCHUNK 12
#define TPC 12           // 11 chunks of 12 + 1 chunk of 5

typedef __attribute__((ext_vector_type(8))) short short8;
typedef __attribute__((ext_vector_type(16))) float floatx16;

#if defined(__has_builtin)
#  if __has_builtin(__builtin_amdgcn_exp2f)
#    define FAST_EXP2(x) __builtin_amdgcn_exp2f(x)
#  endif
#endif
#ifndef FAST_EXP2
#  define FAST_EXP2(x) exp2f(x)
#endif

// Fused: Q-prep (blocks 0..18431), K-prep (18432..20735), zero l/w/mean (20736..20879).
__global__ __launch_bounds__(256)
void prep_all(const float* __restrict__ mut, const float* __restrict__ W_in,
              const float* __restrict__ b_in, const float* __restrict__ key,
              __hip_bfloat16* __restrict__ Qb, __hip_bfloat16* __restrict__ Kb,
              float* __restrict__ l, float* __restrict__ w, float* __restrict__ meanbuf) {
    int bx = blockIdx.x, t = threadIdx.x;
    if (bx < 18432) {                      // Q: 8*4608*128 elems
        int idx = bx * 256 + t;
        int d = idx & 127;
        int g = (idx >> 7) % GPAD;
        int b = idx / (GPAD * 128);
        float v = 0.f;
        if (g < NUM_GENES) {
            const float* m = mut + ((size_t)b * NUM_GENES + g) * 4;
            v = b_in[d] + m[0] * W_in[d] + m[1] * W_in[128 + d]
                        + m[2] * W_in[256 + d] + m[3] * W_in[384 + d];
            v *= (0.08838834764831845f * 1.4426950408889634f);   // 1/sqrt(128) * log2(e)
        }
        Qb[idx] = __float2bfloat16(v);
    } else if (bx < 20736) {               // K: 4608*128 elems
        int idx = (bx - 18432) * 256 + t;
        int g = idx >> 7;
        float v = (g < NUM_GENES) ? key[idx] : 0.f;
        Kb[idx] = __float2bfloat16(v);
    } else {                               // zero: 144 blocks * 256 = 36864 = 8*4608
        int i = (bx - 20736) * 256 + t;
        l[i] = 0.f;
        w[i] = 0.f;
        if (i < 1024) meanbuf[i] = 0.f;
    }
}

// Unified phase kernel, 64 resident rows/wave, double-buffered LDS (1 barrier/tile).
// PB=false: resident=Q (per b), stream=K, out l[b,q] += rowsum(exp2(S))
// PB=true : resident=K, stream=Q (per b), out w[b,k] += rowsum(exp2(S)/l[q])
// A/B frag: lane holds row/col (lane&31), 16B at byte dsl*32 + (lane>>5)*16.
// C/D: col=lane&31, row=(r&3)+8*(r>>2)+4*(lane>>5).
template <bool PB>
__global__ __launch_bounds__(256)
void phase_kernel(const __hip_bfloat16* __restrict__ Qb,
                  const __hip_bfloat16* __restrict__ Kb,
                  const float* __restrict__ lsum,
                  float* __restrict__ out) {
    __shared__ __align__(16) char tile[2][32 * LDS_STRIDE];

    int rb    = blockIdx.x;   // resident 256-row block, 0..17
    int chunk = blockIdx.y;   // 0..11 over stream tiles
    int b     = blockIdx.z;   // batch

    const char* resident = (const char*)(PB ? Kb : (Qb + (size_t)b * GPAD * DM));
    const char* stream   = (const char*)(PB ? (Qb + (size_t)b * GPAD * DM) : Kb);

    int t = threadIdx.x;
    int lane = t & 63, wid = t >> 6;
    int m = lane & 31, half = lane >> 5;

    // Resident A fragments: 64 rows per wave (two 32-row groups), in VGPRs.
    short8 afrag[2][8];
#pragma unroll
    for (int g = 0; g < 2; ++g) {
        const char* arow = resident + (size_t)(rb * 256 + wid * 64 + g * 32 + m) * ROWB;
#pragma unroll
        for (int dsl = 0; dsl < 8; ++dsl)
            afrag[g][dsl] = *(const short8*)(arow + dsl * 32 + half * 16);
    }

    float lacc[2][16];
#pragma unroll
    for (int g = 0; g < 2; ++g)
#pragma unroll
        for (int r = 0; r < 16; ++r) lacc[g][r] = 0.f;

    int t0 = chunk * TPC;
    int t1 = min(NTILES, t0 + TPC);
    int sr = t >> 3, sc = t & 7;   // staging: thread -> (row, 32B chunk)
    int soff = sr * LDS_STRIDE + sc * 32;

    // Pre-loop: load tile t0 and write into buf 0.
    {
        const char* src = stream + (size_t)(t0 * 32 + sr) * ROWB + sc * 32;
        float4 v0 = *(const float4*)src;
        float4 v1 = *(const float4*)(src + 16);
        *(float4*)(tile[0] + soff) = v0;
        *(float4*)(tile[0] + soff + 16) = v1;
    }

    int p = 0;
    for (int kt = t0; kt < t1; ++kt) {
        bool more = (kt + 1 < t1);
        float4 v0, v1;
        if (more) {   // issue next tile's global loads; latency hidden by MFMA below
            const char* s2 = stream + (size_t)((kt + 1) * 32 + sr) * ROWB + sc * 32;
            v0 = *(const float4*)s2;
            v1 = *(const float4*)(s2 + 16);
        }
        __syncthreads();   // buf[p] fully written; prior reads of buf[p^1] done

        floatx16 acc0, acc1;
#pragma unroll
        for (int r = 0; r < 16; ++r) { acc0[r] = 0.f; acc1[r] = 0.f; }
#pragma unroll
        for (int dsl = 0; dsl < 8; ++dsl) {
            short8 bfrag = *(const short8*)(tile[p] + m * LDS_STRIDE + dsl * 32 + half * 16);
            acc0 = __builtin_amdgcn_mfma_f32_32x32x16_bf16(afrag[0][dsl], bfrag, acc0, 0, 0, 0);
            acc1 = __builtin_amdgcn_mfma_f32_32x32x16_bf16(afrag[1][dsl], bfrag, acc1, 0, 0, 0);
        }

        if (more) {   // stage next tile into the other buffer (no barrier needed here)
            *(float4*)(tile[p ^ 1] + soff) = v0;
            *(float4*)(tile[p ^ 1] + soff + 16) = v1;
        }

        if (PB) {
            float scl = 1.0f / lsum[b * GPAD + kt * 32 + m];   // col = streamed q index
#pragma unroll
            for (int r = 0; r < 16; ++r) {
                lacc[0][r] = fmaf(FAST_EXP2(acc0[r]), scl, lacc[0][r]);
                lacc[1][r] = fmaf(FAST_EXP2(acc1[r]), scl, lacc[1][r]);
            }
        } else {
#pragma unroll
            for (int r = 0; r < 16; ++r) {
                lacc[0][r] += FAST_EXP2(acc0[r]);
                lacc[1][r] += FAST_EXP2(acc1[r]);
            }
        }
        p ^= 1;
    }

    // Reduce across the 32 columns (lanes sharing the same 'half').
#pragma unroll
    for (int off = 1; off <= 16; off <<= 1)
#pragma unroll
        for (int g = 0; g < 2; ++g)
#pragma unroll
            for (int r = 0; r < 16; ++r)
                lacc[g][r] += __shfl_xor(lacc[g][r], off, 64);

    if (m == 0) {   // lanes 0 and 32 hold sums for rows (+0 / +4)
#pragma unroll
        for (int g = 0; g < 2; ++g) {
            float* ob = out + b * GPAD + rb * 256 + wid * 64 + g * 32 + 4 * half;
#pragma unroll
            for (int r = 0; r < 16; ++r)
                atomicAdd(ob + (r & 3) + 8 * (r >> 2), lacc[g][r]);
        }
    }
}

// mean partials: meanbuf[b,d] += sum_{g in block's 128 rows} w[b,g] * V[g,d]
__global__ __launch_bounds__(256)
void mean_k(const float* __restrict__ w, const float* __restrict__ V,
            float* __restrict__ meanbuf) {
    int rb = blockIdx.x, b = blockIdx.y;
    int t = threadIdx.x;
    int d = t & 127, half = t >> 7;        // each half-block covers 64 gene rows
    int g0 = rb * 128 + half * 64;
    int nv = NUM_GENES - g0;               // valid rows in this half (can be <=0)
    if (nv > 64) nv = 64;
    float a = 0.f;
    if (nv > 0) {
        const float* wb = w + b * GPAD + g0;
        const float* Vp = V + (size_t)g0 * 128 + d;
        for (int k = 0; k < nv; ++k)
            a += wb[k] * Vp[(size_t)k * 128];
    }
    atomicAdd(meanbuf + b * 128 + d, a);
}

// h = gelu(mean/G @ W1 + b1) ; out = h@W2 + b2.  grid 8, block 64.
__global__ void mlp_k(const float* __restrict__ meanbuf,
                      const float* __restrict__ W1, const float* __restrict__ b1,
                      const float* __restrict__ W2, const float* __restrict__ b2,
                      float* __restrict__ out) {
    int b = blockIdx.x, t = threadIdx.x;
    __shared__ float sh[64];
    const float* mb = meanbuf + b * 128;
    float s = b1[t];
    for (int d = 0; d < 128; ++d)
        s += (mb[d] * (1.0f / 4384.0f)) * W1[d * 64 + t];
    sh[t] = 0.5f * s * (1.0f + erff(s * 0.70710678118654752f));   // exact gelu
    __syncthreads();
    if (t < 26) {
        float o = b2[t];
        for (int j = 0; j < 64; ++j) o += sh[j] * W2[j * 26 + t];
        out[b * 26 + t] = o;
    }
}

extern "C" void kernel_launch(void* const* d_in, const int* in_sizes, int n_in,
                              void* d_out, int out_size, void* d_ws, size_t ws_size,
                              hipStream_t stream) {
    const float* mut  = (const float*)d_in[0];   // [8,4384,4]
    const float* V    = (const float*)d_in[1];   // [4384,128]
    const float* W_in = (const float*)d_in[2];   // [4,128]
    const float* b_in = (const float*)d_in[3];   // [128]
    const float* key  = (const float*)d_in[4];   // [4384,128]
    const float* W1   = (const float*)d_in[5];   // [128,64]
    const float* b1   = (const float*)d_in[6];   // [64]
    const float* W2   = (const float*)d_in[7];   // [64,26]
    const float* b2   = (const float*)d_in[8];   // [26]
    float* out = (float*)d_out;                  // [8,26]

    char* ws = (char*)d_ws;
    __hip_bfloat16* Qb = (__hip_bfloat16*)(ws);                    // 8*4608*128*2 = 9,437,184
    __hip_bfloat16* Kb = (__hip_bfloat16*)(ws + 9437184);          // 4608*128*2   = 1,179,648
    float* lbuf        = (float*)(ws + 10616832);                  // 8*4608*4     =   147,456
    float* wbuf        = (float*)(ws + 10764288);                  // 8*4608*4     =   147,456
    float* meanbuf     = (float*)(ws + 10911744);                  // 8*128*4      =     4,096

    prep_all<<<20880, 256, 0, stream>>>(mut, W_in, b_in, key, Qb, Kb, lbuf, wbuf, meanbuf);

    dim3 grid(RB_BLOCKS, NCHUNK, 8);
    phase_kernel<false><<<grid, 256, 0, stream>>>(Qb, Kb, lbuf, lbuf);  // l = rowsum exp2(S)
    phase_kernel<true><<<grid, 256, 0, stream>>>(Qb, Kb, lbuf, wbuf);   // w = colsum softmax (1/l inline)

    mean_k<<<dim3(35, 8), 256, 0, stream>>>(wbuf, V, meanbuf);
    mlp_k<<<8, 64, 0, stream>>>(meanbuf, W1, b1, W2, b2, out);
}

// Round 5
// 211.998 us; speedup vs baseline: 1.1497x; 1.1497x over previous
//
#include <hip/hip_runtime.h>
#include <hip/hip_bf16.h>

#define NUM_GENES 4384
#define GPAD 4608        // 18 * 256 (pad resident dim; 256 rows per block)
#define DM 128
#define ROWB 256         // bytes per bf16 row (128*2)
#define LDS_STRIDE 272   // 256 + 16B pad (b128 4-way = data floor, not a real conflict)
#define NTILES 137       // 4384 / 32 (stream dim exact; pad rows never streamed)
#define RB_BLOCKS 18     // GPAD / 256
#define NCHUNK 6
#define TPC 23           // 5 chunks of 23 + 1 chunk of 22

typedef __attribute__((ext_vector_type(8))) short short8;
typedef __attribute__((ext_vector_type(16))) float floatx16;

#if defined(__has_builtin)
#  if __has_builtin(__builtin_amdgcn_exp2f)
#    define FAST_EXP2(x) __builtin_amdgcn_exp2f(x)
#  endif
#endif
#ifndef FAST_EXP2
#  define FAST_EXP2(x) exp2f(x)
#endif

static __device__ __forceinline__ short bf16bits(float x) {
    __hip_bfloat16 h = __float2bfloat16(x);
    return *(short*)&h;
}

// Fused prep, 8 outputs/thread, 16B stores.
// Q: blocks [0,2304)  K: [2304,2592)  zero l/w/mean: [2592,2610)
__global__ __launch_bounds__(256)
void prep_all(const float* __restrict__ mut, const float* __restrict__ W_in,
              const float* __restrict__ b_in, const float* __restrict__ key,
              __hip_bfloat16* __restrict__ Qb, __hip_bfloat16* __restrict__ Kb,
              float* __restrict__ l, float* __restrict__ w, float* __restrict__ meanbuf) {
    int bx = blockIdx.x, t = threadIdx.x;
    if (bx < 2304) {                        // Q: 8*4608*128 elems, 8 per thread
        int i = bx * 256 + t;               // [0, 589824)
        int d0 = (i & 15) * 8;
        int g = (i >> 4) % GPAD;
        int b = i / (GPAD * 16);
        short8 o;
        if (g < NUM_GENES) {
            const float4 mv = *(const float4*)(mut + ((size_t)b * NUM_GENES + g) * 4);
            const float sc = 0.08838834764831845f * 1.4426950408889634f; // 1/sqrt(128)*log2(e)
#pragma unroll
            for (int j = 0; j < 8; ++j) {
                int d = d0 + j;
                float v = b_in[d] + mv.x * W_in[d] + mv.y * W_in[128 + d]
                                  + mv.z * W_in[256 + d] + mv.w * W_in[384 + d];
                o[j] = bf16bits(v * sc);
            }
        } else {
#pragma unroll
            for (int j = 0; j < 8; ++j) o[j] = 0;
        }
        *(short8*)((short*)Qb + (size_t)i * 8) = o;
    } else if (bx < 2592) {                 // K: 4608*128 elems, 8 per thread
        int i = (bx - 2304) * 256 + t;      // [0, 73728)
        int g = i >> 4;
        short8 o;
        if (g < NUM_GENES) {
            const float4 k0 = *(const float4*)(key + (size_t)i * 8);
            const float4 k1 = *(const float4*)(key + (size_t)i * 8 + 4);
            o[0] = bf16bits(k0.x); o[1] = bf16bits(k0.y);
            o[2] = bf16bits(k0.z); o[3] = bf16bits(k0.w);
            o[4] = bf16bits(k1.x); o[5] = bf16bits(k1.y);
            o[6] = bf16bits(k1.z); o[7] = bf16bits(k1.w);
        } else {
#pragma unroll
            for (int j = 0; j < 8; ++j) o[j] = 0;
        }
        *(short8*)((short*)Kb + (size_t)i * 8) = o;
    } else {                                // zero: 18 blocks, 8 floats/thread each for l,w
        int i = (bx - 2592) * 256 + t;      // [0, 4608) -> covers 36864 floats
        float4 z = {0.f, 0.f, 0.f, 0.f};
        *(float4*)(l + (size_t)i * 8) = z;
        *(float4*)(l + (size_t)i * 8 + 4) = z;
        *(float4*)(w + (size_t)i * 8) = z;
        *(float4*)(w + (size_t)i * 8 + 4) = z;
        if (bx == 2592 && t < 128) {        // meanbuf: 1024 floats
            *(float4*)(meanbuf + t * 8) = z;
            *(float4*)(meanbuf + t * 8 + 4) = z;
        }
    }
}

// Unified phase kernel, 64 resident rows/wave, double-buffered LDS (1 barrier/tile).
// PB=false: resident=Q (per b), stream=K, out l[b,q] += rowsum(exp2(S))
// PB=true : resident=K, stream=Q (per b), out w[b,k] += rowsum(exp2(S)/l[q])
// A/B frag: lane holds row/col (lane&31), 16B at byte dsl*32 + (lane>>5)*16.
// C/D: col=lane&31, row=(r&3)+8*(r>>2)+4*(lane>>5).
template <bool PB>
__global__ __launch_bounds__(256)
void phase_kernel(const __hip_bfloat16* __restrict__ Qb,
                  const __hip_bfloat16* __restrict__ Kb,
                  const float* __restrict__ lsum,
                  float* __restrict__ out) {
    __shared__ __align__(16) char tile[2][32 * LDS_STRIDE];

    int rb    = blockIdx.x;   // resident 256-row block, 0..17
    int chunk = blockIdx.y;   // 0..5 over stream tiles
    int b     = blockIdx.z;   // batch

    const char* resident = (const char*)(PB ? Kb : (Qb + (size_t)b * GPAD * DM));
    const char* stream   = (const char*)(PB ? (Qb + (size_t)b * GPAD * DM) : Kb);

    int t = threadIdx.x;
    int lane = t & 63, wid = t >> 6;
    int m = lane & 31, half = lane >> 5;

    // Resident A fragments: 64 rows per wave (two 32-row groups), in VGPRs.
    short8 afrag[2][8];
#pragma unroll
    for (int g = 0; g < 2; ++g) {
        const char* arow = resident + (size_t)(rb * 256 + wid * 64 + g * 32 + m) * ROWB;
#pragma unroll
        for (int dsl = 0; dsl < 8; ++dsl)
            afrag[g][dsl] = *(const short8*)(arow + dsl * 32 + half * 16);
    }

    float lacc[2][16];
#pragma unroll
    for (int g = 0; g < 2; ++g)
#pragma unroll
        for (int r = 0; r < 16; ++r) lacc[g][r] = 0.f;

    int t0 = chunk * TPC;
    int t1 = min(NTILES, t0 + TPC);
    int sr = t >> 3, sc = t & 7;   // staging: thread -> (row, 32B chunk)
    int soff = sr * LDS_STRIDE + sc * 32;

    // Pre-loop: load tile t0 and write into buf 0.
    {
        const char* src = stream + (size_t)(t0 * 32 + sr) * ROWB + sc * 32;
        float4 v0 = *(const float4*)src;
        float4 v1 = *(const float4*)(src + 16);
        *(float4*)(tile[0] + soff) = v0;
        *(float4*)(tile[0] + soff + 16) = v1;
    }

    int p = 0;
    for (int kt = t0; kt < t1; ++kt) {
        bool more = (kt + 1 < t1);
        float4 v0, v1;
        if (more) {   // issue next tile's global loads; latency hidden by MFMA below
            const char* s2 = stream + (size_t)((kt + 1) * 32 + sr) * ROWB + sc * 32;
            v0 = *(const float4*)s2;
            v1 = *(const float4*)(s2 + 16);
        }
        __syncthreads();   // buf[p] fully written; prior reads of buf[p^1] done

        floatx16 acc0, acc1;
#pragma unroll
        for (int r = 0; r < 16; ++r) { acc0[r] = 0.f; acc1[r] = 0.f; }
#pragma unroll
        for (int dsl = 0; dsl < 8; ++dsl) {
            short8 bfrag = *(const short8*)(tile[p] + m * LDS_STRIDE + dsl * 32 + half * 16);
            acc0 = __builtin_amdgcn_mfma_f32_32x32x16_bf16(afrag[0][dsl], bfrag, acc0, 0, 0, 0);
            acc1 = __builtin_amdgcn_mfma_f32_32x32x16_bf16(afrag[1][dsl], bfrag, acc1, 0, 0, 0);
        }

        if (more) {   // stage next tile into the other buffer (no barrier needed here)
            *(float4*)(tile[p ^ 1] + soff) = v0;
            *(float4*)(tile[p ^ 1] + soff + 16) = v1;
        }

        if (PB) {
            float scl = 1.0f / lsum[b * GPAD + kt * 32 + m];   // col = streamed q index
#pragma unroll
            for (int r = 0; r < 16; ++r) {
                lacc[0][r] = fmaf(FAST_EXP2(acc0[r]), scl, lacc[0][r]);
                lacc[1][r] = fmaf(FAST_EXP2(acc1[r]), scl, lacc[1][r]);
            }
        } else {
#pragma unroll
            for (int r = 0; r < 16; ++r) {
                lacc[0][r] += FAST_EXP2(acc0[r]);
                lacc[1][r] += FAST_EXP2(acc1[r]);
            }
        }
        p ^= 1;
    }

    // Reduce across the 32 columns (lanes sharing the same 'half').
#pragma unroll
    for (int off = 1; off <= 16; off <<= 1)
#pragma unroll
        for (int g = 0; g < 2; ++g)
#pragma unroll
            for (int r = 0; r < 16; ++r)
                lacc[g][r] += __shfl_xor(lacc[g][r], off, 64);

    if (m == 0) {   // lanes 0 and 32 hold sums for rows (+0 / +4)
#pragma unroll
        for (int g = 0; g < 2; ++g) {
            float* ob = out + b * GPAD + rb * 256 + wid * 64 + g * 32 + 4 * half;
#pragma unroll
            for (int r = 0; r < 16; ++r)
                atomicAdd(ob + (r & 3) + 8 * (r >> 2), lacc[g][r]);
        }
    }
}

// mean partials: meanbuf[b,d] += sum_{g in block's 128 rows} w[b,g] * V[g,d]
__global__ __launch_bounds__(256)
void mean_k(const float* __restrict__ w, const float* __restrict__ V,
            float* __restrict__ meanbuf) {
    int rb = blockIdx.x, b = blockIdx.y;
    int t = threadIdx.x;
    int d = t & 127, half = t >> 7;        // each half-block covers 64 gene rows
    int g0 = rb * 128 + half * 64;
    int nv = NUM_GENES - g0;               // valid rows in this half (can be <=0)
    if (nv > 64) nv = 64;
    float a = 0.f;
    if (nv > 0) {
        const float* wb = w + b * GPAD + g0;
        const float* Vp = V + (size_t)g0 * 128 + d;
        for (int k = 0; k < nv; ++k)
            a += wb[k] * Vp[(size_t)k * 128];
    }
    atomicAdd(meanbuf + b * 128 + d, a);
}

// h = gelu(mean/G @ W1 + b1) ; out = h@W2 + b2.  grid 8, block 64.
__global__ void mlp_k(const float* __restrict__ meanbuf,
                      const float* __restrict__ W1, const float* __restrict__ b1,
                      const float* __restrict__ W2, const float* __restrict__ b2,
                      float* __restrict__ out) {
    int b = blockIdx.x, t = threadIdx.x;
    __shared__ float sh[64];
    const float* mb = meanbuf + b * 128;
    float s = b1[t];
    for (int d = 0; d < 128; ++d)
        s += (mb[d] * (1.0f / 4384.0f)) * W1[d * 64 + t];
    sh[t] = 0.5f * s * (1.0f + erff(s * 0.70710678118654752f));   // exact gelu
    __syncthreads();
    if (t < 26) {
        float o = b2[t];
        for (int j = 0; j < 64; ++j) o += sh[j] * W2[j * 26 + t];
        out[b * 26 + t] = o;
    }
}

extern "C" void kernel_launch(void* const* d_in, const int* in_sizes, int n_in,
                              void* d_out, int out_size, void* d_ws, size_t ws_size,
                              hipStream_t stream) {
    const float* mut  = (const float*)d_in[0];   // [8,4384,4]
    const float* V    = (const float*)d_in[1];   // [4384,128]
    const float* W_in = (const float*)d_in[2];   // [4,128]
    const float* b_in = (const float*)d_in[3];   // [128]
    const float* key  = (const float*)d_in[4];   // [4384,128]
    const float* W1   = (const float*)d_in[5];   // [128,64]
    const float* b1   = (const float*)d_in[6];   // [64]
    const float* W2   = (const float*)d_in[7];   // [64,26]
    const float* b2   = (const float*)d_in[8];   // [26]
    float* out = (float*)d_out;                  // [8,26]

    char* ws = (char*)d_ws;
    __hip_bfloat16* Qb = (__hip_bfloat16*)(ws);                    // 8*4608*128*2 = 9,437,184
    __hip_bfloat16* Kb = (__hip_bfloat16*)(ws + 9437184);          // 4608*128*2   = 1,179,648
    float* lbuf        = (float*)(ws + 10616832);                  // 8*4608*4     =   147,456
    float* wbuf        = (float*)(ws + 10764288);                  // 8*4608*4     =   147,456
    float* meanbuf     = (float*)(ws + 10911744);                  // 8*128*4      =     4,096

    prep_all<<<2610, 256, 0, stream>>>(mut, W_in, b_in, key, Qb, Kb, lbuf, wbuf, meanbuf);

    dim3 grid(RB_BLOCKS, NCHUNK, 8);
    phase_kernel<false><<<grid, 256, 0, stream>>>(Qb, Kb, lbuf, lbuf);  // l = rowsum exp2(S)
    phase_kernel<true><<<grid, 256, 0, stream>>>(Qb, Kb, lbuf, wbuf);   // w = colsum softmax (1/l inline)

    mean_k<<<dim3(35, 8), 256, 0, stream>>>(wbuf, V, meanbuf);
    mlp_k<<<8, 64, 0, stream>>>(meanbuf, W1, b1, W2, b2, out);
}